// Round 1
// baseline (132.617 us; speedup 1.0000x reference)
//
#include <hip/hip_runtime.h>

// Inv2d (involution): B=4, C=128, H=W=64, G=8 groups (16 ch/group),
// K=7, dilation=2, pad=6, reduce C->32, span 32->392 (=7*7*8).
//
// Kernel A: red[b][o][p] = b_reduce[o] + sum_c x[b][c][p] * w_reduce[o][c]
// Kernel B (fused): per pixel+group, compute the 49 dynamic kernel values
//   from red on the fly (w_span is block-uniform -> scalar loads) and apply
//   them to the 16 channels of the group. ker tensor (25.7 MB) never hits
//   memory.

#define HW 4096   // 64*64
#define NC 128
#define NR 32     // reduced channels
#define NG 8
#define CG 16     // channels per group

__global__ __launch_bounds__(256) void red_gen(
    const float* __restrict__ x, const float* __restrict__ w_reduce,
    const float* __restrict__ b_reduce, float* __restrict__ red) {
  // grid: pchunk(16) x otile(8) x b(4) = 512 blocks
  int blk = blockIdx.x;
  int pchunk = blk & 15;
  int ot = (blk >> 4) & 7;      // 8 tiles of 4 output channels
  int b = blk >> 7;
  int p = pchunk * 256 + threadIdx.x;
  int o0 = ot * 4;

  const float* xp = x + b * NC * HW + p;
  float acc[4];
#pragma unroll
  for (int q = 0; q < 4; ++q) acc[q] = b_reduce[o0 + q];

#pragma unroll 8
  for (int c = 0; c < NC; ++c) {
    float xv = xp[c * HW];
#pragma unroll
    for (int q = 0; q < 4; ++q) acc[q] += xv * w_reduce[(o0 + q) * NC + c];
  }

  float* rp = red + (b * NR + o0) * HW + p;
#pragma unroll
  for (int q = 0; q < 4; ++q) rp[q * HW] = acc[q];
}

__global__ __launch_bounds__(256) void inv_apply(
    const float* __restrict__ x, const float* __restrict__ red,
    const float* __restrict__ w_span, const float* __restrict__ b_span,
    float* __restrict__ out) {
  // grid: pchunk(16) x g(8) x b(4) = 512 blocks; thread = one pixel, one group
  int blk = blockIdx.x;
  int pchunk = blk & 15;
  int g = (blk >> 4) & 7;
  int b = blk >> 7;
  int p = pchunk * 256 + threadIdx.x;
  int h = p >> 6;
  int w = p & 63;

  // pixel's reduced features -> registers
  float r[NR];
  const float* rp = red + b * NR * HW + p;
#pragma unroll
  for (int o = 0; o < NR; ++o) r[o] = rp[o * HW];

  const float* xb = x + (b * NC + g * CG) * HW;
  float acc[CG];
#pragma unroll
  for (int c = 0; c < CG; ++c) acc[c] = 0.f;

  for (int i = 0; i < 7; ++i) {
    int hh = h + 2 * i - 6;
    bool hv = (unsigned)hh < 64u;
#pragma unroll
    for (int j = 0; j < 7; ++j) {
      int ww = w + 2 * j - 6;
      bool v = hv && ((unsigned)ww < 64u);
      int kidx = g * 49 + i * 7 + j;
      // dynamic kernel value for this (pixel, g, tap) — w_span row is
      // block-uniform (g fixed) -> scalar loads
      const float* wr = w_span + kidx * NR;
      float kv = b_span[kidx];
#pragma unroll
      for (int o = 0; o < NR; ++o) kv += r[o] * wr[o];
      // branchless boundary: clamp address in-bounds, zero the kernel value
      kv = v ? kv : 0.f;
      int off = v ? (hh * 64 + ww) : 0;
#pragma unroll
      for (int c = 0; c < CG; ++c) acc[c] += xb[c * HW + off] * kv;
    }
  }

  float* op = out + (b * NC + g * CG) * HW + p;
#pragma unroll
  for (int c = 0; c < CG; ++c) op[c * HW] = acc[c];
}

extern "C" void kernel_launch(void* const* d_in, const int* in_sizes, int n_in,
                              void* d_out, int out_size, void* d_ws, size_t ws_size,
                              hipStream_t stream) {
  const float* x        = (const float*)d_in[0];  // [4,128,64,64]
  const float* w_reduce = (const float*)d_in[1];  // [32,128]
  const float* b_reduce = (const float*)d_in[2];  // [32]
  const float* w_span   = (const float*)d_in[3];  // [392,32]
  const float* b_span   = (const float*)d_in[4];  // [392]
  float* out = (float*)d_out;                     // [4,128,64,64]

  float* red = (float*)d_ws;                      // [4,32,64,64] = 2 MB

  red_gen<<<512, 256, 0, stream>>>(x, w_reduce, b_reduce, red);
  inv_apply<<<512, 256, 0, stream>>>(x, red, w_span, b_span, out);
}

// Round 2
// 114.957 us; speedup vs baseline: 1.1536x; 1.1536x over previous
//
#include <hip/hip_runtime.h>

// Inv2d (involution): B=4, C=128, H=W=64, G=8 (16 ch/group), K=7, dil=2,
// pad=6, reduce 128->32, span 32->392.
//
// Round 2: latency-oriented restructure (both kernels were latency-bound:
// VALUBusy 25%, HBM 5%, occupancy 10%).
//  - red_gen: 16-deep explicit load pipeline, x2 outer unroll -> up to 32
//    outstanding loads/wave.
//  - inv_apply: phase 1 computes all 49 dynamic kernel values into regs
//    (split accumulator chains); boundary = clamp pixel index + zero kv
//    (loads stay in-bounds, math exact). Phase 2: per channel, uniform
//    (SGPR) base + 49 independent loads via precomputed per-lane offsets,
//    16 independent acc chains. Removes per-load 64-bit address VALU.

#define HW 4096   // 64*64
#define NC 128
#define NR 32     // reduced channels
#define NG 8
#define CG 16     // channels per group
#define KK 49

__global__ __launch_bounds__(256) void red_gen(
    const float* __restrict__ x, const float* __restrict__ w_reduce,
    const float* __restrict__ b_reduce, float* __restrict__ red) {
  // grid: pchunk(16) x otile(8) x b(4) = 512 blocks
  int blk = blockIdx.x;
  int pchunk = blk & 15;
  int ot = (blk >> 4) & 7;      // 8 tiles of 4 output channels
  int b = blk >> 7;
  int p = pchunk * 256 + threadIdx.x;
  int o0 = ot * 4;

  const float* xp = x + b * NC * HW + p;
  float acc[4];
#pragma unroll
  for (int q = 0; q < 4; ++q) acc[q] = b_reduce[o0 + q];

#pragma unroll 2
  for (int cb = 0; cb < NC; cb += 16) {
    float xv[16];
#pragma unroll
    for (int u = 0; u < 16; ++u) xv[u] = xp[(cb + u) * HW];
#pragma unroll
    for (int u = 0; u < 16; ++u) {
#pragma unroll
      for (int q = 0; q < 4; ++q)
        acc[q] += xv[u] * w_reduce[(o0 + q) * NC + cb + u];
    }
  }

  float* rp = red + (b * NR + o0) * HW + p;
#pragma unroll
  for (int q = 0; q < 4; ++q) rp[q * HW] = acc[q];
}

__global__ __launch_bounds__(256) void inv_apply(
    const float* __restrict__ x, const float* __restrict__ red,
    const float* __restrict__ w_span, const float* __restrict__ b_span,
    float* __restrict__ out) {
  // grid: pchunk(16) x g(8) x b(4) = 512 blocks; thread = one pixel, one group
  int blk = blockIdx.x;
  int pchunk = blk & 15;
  int g = (blk >> 4) & 7;
  int b = blk >> 7;
  int p = pchunk * 256 + threadIdx.x;
  int h = p >> 6;
  int w = p & 63;

  // pixel's reduced features -> registers (coalesced: lanes = consecutive p)
  float r[NR];
  const float* rp = red + b * NR * HW + p;
#pragma unroll
  for (int o = 0; o < NR; ++o) r[o] = rp[o * HW];

  // Phase 1: all 49 dynamic kernel values + clamped per-lane pixel offsets.
  float kv[KK];
  int voff[KK];
#pragma unroll
  for (int t = 0; t < KK; ++t) {
    const int i = t / 7, j = t % 7;           // compile-time after unroll
    int hh = h + 2 * i - 6;
    int ww = w + 2 * j - 6;
    bool v = ((unsigned)hh < 64u) && ((unsigned)ww < 64u);
    int q = p + (2 * i - 6) * 64 + (2 * j - 6);
    q = min(max(q, 0), HW - 1);               // in-bounds; kv=0 kills garbage
    voff[t] = q;
    const float* wrow = w_span + (g * KK + t) * NR;  // block-uniform -> s_load
    float s0 = b_span[g * KK + t], s1 = 0.f;
#pragma unroll
    for (int o = 0; o < NR; o += 2) {         // 2 chains, 16 deep each
      s0 += r[o] * wrow[o];
      s1 += r[o + 1] * wrow[o + 1];
    }
    kv[t] = v ? (s0 + s1) : 0.f;
  }

  // Phase 2: per channel, uniform base + 49 independent indexed loads.
  const float* xg = x + (b * NC + g * CG) * HW;
  float acc[CG];
#pragma unroll
  for (int c = 0; c < CG; ++c) acc[c] = 0.f;

#pragma unroll
  for (int c = 0; c < CG; ++c) {
    const float* xc = xg + c * HW;            // block-uniform (SGPR base)
#pragma unroll
    for (int t = 0; t < KK; ++t) acc[c] += xc[voff[t]] * kv[t];
  }

  float* op = out + (b * NC + g * CG) * HW + p;
#pragma unroll
  for (int c = 0; c < CG; ++c) op[c * HW] = acc[c];
}

extern "C" void kernel_launch(void* const* d_in, const int* in_sizes, int n_in,
                              void* d_out, int out_size, void* d_ws, size_t ws_size,
                              hipStream_t stream) {
  const float* x        = (const float*)d_in[0];  // [4,128,64,64]
  const float* w_reduce = (const float*)d_in[1];  // [32,128]
  const float* b_reduce = (const float*)d_in[2];  // [32]
  const float* w_span   = (const float*)d_in[3];  // [392,32]
  const float* b_span   = (const float*)d_in[4];  // [392]
  float* out = (float*)d_out;                     // [4,128,64,64]

  float* red = (float*)d_ws;                      // [4,32,64,64] = 2 MB

  red_gen<<<512, 256, 0, stream>>>(x, w_reduce, b_reduce, red);
  inv_apply<<<512, 256, 0, stream>>>(x, red, w_span, b_span, out);
}